// Round 7
// baseline (725.881 us; speedup 1.0000x reference)
//
#include <hip/hip_runtime.h>
#include <hip/hip_bf16.h>

typedef __attribute__((ext_vector_type(4))) float  f32x4;
typedef __attribute__((ext_vector_type(8))) short  s16x8;
typedef __attribute__((ext_vector_type(4))) short  s16x4;

#define NV 8192
#define NE 8192
#define DIM 512

__device__ inline short f2bf(float x) {
    unsigned u = __float_as_uint(x);
    u += 0x7fffu + ((u >> 16) & 1u);   // round-to-nearest-even
    return (short)(u >> 16);
}
__device__ inline float bf2f(short s) {
    return __uint_as_float(((unsigned)(unsigned short)s) << 16);
}

// ---------------- gate[e] = sum_c H_e[e,c] * p[c] ----------------
__global__ void gate_kernel(const float* __restrict__ He, const float* __restrict__ p,
                            float* __restrict__ gate) {
    int row  = blockIdx.x * 4 + (threadIdx.x >> 6);
    int lane = threadIdx.x & 63;
    const float* r = He + (size_t)row * DIM + lane * 8;
    float4 a0 = *(const float4*)r;
    float4 a1 = *(const float4*)(r + 4);
    float4 p0 = *(const float4*)(p + lane * 8);
    float4 p1 = *(const float4*)(p + lane * 8 + 4);
    float s = a0.x*p0.x + a0.y*p0.y + a0.z*p0.z + a0.w*p0.w
            + a1.x*p1.x + a1.y*p1.y + a1.z*p1.z + a1.w*p1.w;
    #pragma unroll
    for (int off = 32; off; off >>= 1) s += __shfl_down(s, off);
    if (lane == 0) gate[row] = s;
}

// ------------- Tg = bf16(T * gate[col]), Tb = bf16(T) -------------
__global__ void convert_T(const float* __restrict__ T, const float* __restrict__ gate,
                          short* __restrict__ Tg, short* __restrict__ Tb) {
    size_t gid  = (size_t)blockIdx.x * blockDim.x + threadIdx.x;
    size_t base = gid * 8;
    int col = (int)(base & (NE - 1));
    float4 t0 = *(const float4*)(T + base);
    float4 t1 = *(const float4*)(T + base + 4);
    float4 g0 = *(const float4*)(gate + col);
    float4 g1 = *(const float4*)(gate + col + 4);
    s16x8 vb, vg;
    vb[0]=f2bf(t0.x); vb[1]=f2bf(t0.y); vb[2]=f2bf(t0.z); vb[3]=f2bf(t0.w);
    vb[4]=f2bf(t1.x); vb[5]=f2bf(t1.y); vb[6]=f2bf(t1.z); vb[7]=f2bf(t1.w);
    vg[0]=f2bf(t0.x*g0.x); vg[1]=f2bf(t0.y*g0.y); vg[2]=f2bf(t0.z*g0.z); vg[3]=f2bf(t0.w*g0.w);
    vg[4]=f2bf(t1.x*g1.x); vg[5]=f2bf(t1.y*g1.y); vg[6]=f2bf(t1.z*g1.z); vg[7]=f2bf(t1.w*g1.w);
    *(s16x8*)(Tb + base) = vb;
    *(s16x8*)(Tg + base) = vg;
}

// ------------- f32 -> bf16 bulk convert -------------
__global__ void to_bf16(const float* __restrict__ in, short* __restrict__ out) {
    size_t base = ((size_t)blockIdx.x * blockDim.x + threadIdx.x) * 8;
    float4 a = *(const float4*)(in + base);
    float4 b = *(const float4*)(in + base + 4);
    s16x8 v;
    v[0]=f2bf(a.x); v[1]=f2bf(a.y); v[2]=f2bf(a.z); v[3]=f2bf(a.w);
    v[4]=f2bf(b.x); v[5]=f2bf(b.y); v[6]=f2bf(b.z); v[7]=f2bf(b.w);
    *(s16x8*)(out + base) = v;
}

// ------------- WT[c][r] = bf16(W[r][c])  (512x512 transpose-convert) -------------
__global__ void wT_bf16(const float* __restrict__ W, short* __restrict__ WT) {
    __shared__ short t[64][65];
    int rb = blockIdx.x, cb = blockIdx.y;
    int c = threadIdx.x & 63, r0 = threadIdx.x >> 6;
    #pragma unroll
    for (int i = 0; i < 16; ++i) {
        int r = i * 4 + r0;
        t[r][c] = f2bf(W[(size_t)(rb * 64 + r) * DIM + cb * 64 + c]);
    }
    __syncthreads();
    #pragma unroll
    for (int i = 0; i < 16; ++i) {
        int r = i * 4 + r0;
        WT[(size_t)(cb * 64 + r) * DIM + rb * 64 + c] = t[c][r];
    }
}

// ------------- B^T GEMM (128x128 tile) for the small GEMMs -------------
template<int EPI>
__global__ __launch_bounds__(256)
void gemm_bt(const short* __restrict__ A, const short* __restrict__ B,
             int M, int N, int K,
             short* __restrict__ Cb,
             const float* __restrict__ bias, float* __restrict__ Cf) {
    __shared__ short As[128 * 32];
    __shared__ short Bs[128 * 32];

    int nwg = gridDim.x;
    int bid = blockIdx.x;
    int cpx = nwg >> 3;
    bid = (bid & 7) * cpx + (bid >> 3);

    const int nbn = N >> 7;
    const int bm = (bid / nbn) << 7;
    const int bn = (bid % nbn) << 7;
    const int tid  = threadIdx.x;
    const int lane = tid & 63;
    const int wave = tid >> 6;
    const int wrow = (wave >> 1) * 64;
    const int wcol = (wave & 1) * 64;

    f32x4 acc[4][4] = {};

    const int lrow = lane >> 2;
    const int lcol = ((lane & 3) ^ ((lrow >> 1) & 3)) * 8;   // inverse-swizzled source slot

    for (int k0 = 0; k0 < K; k0 += 32) {
        #pragma unroll
        for (int it = 0; it < 2; ++it) {
            int chunk = it * 4 + wave;
            int row = chunk * 16 + lrow;
            __builtin_amdgcn_global_load_lds(
                (const __attribute__((address_space(1))) void*)(A + (size_t)(bm + row) * K + k0 + lcol),
                (__attribute__((address_space(3))) void*)(As + chunk * 512), 16, 0, 0);
            __builtin_amdgcn_global_load_lds(
                (const __attribute__((address_space(1))) void*)(B + (size_t)(bn + row) * K + k0 + lcol),
                (__attribute__((address_space(3))) void*)(Bs + chunk * 512), 16, 0, 0);
        }
        __syncthreads();

        const int fr = lane & 15;
        const int sw = (fr >> 1) & 3;
        const int sa = ((lane >> 4) ^ sw) * 8;               // swizzled read slot
        s16x8 af[4], bfr[4];
        #pragma unroll
        for (int i = 0; i < 4; ++i) {
            af[i]  = *(const s16x8*)&As[(wrow + i * 16 + fr) * 32 + sa];
            bfr[i] = *(const s16x8*)&Bs[(wcol + i * 16 + fr) * 32 + sa];
        }
        #pragma unroll
        for (int i = 0; i < 4; ++i)
            #pragma unroll
            for (int j = 0; j < 4; ++j)
                acc[i][j] = __builtin_amdgcn_mfma_f32_16x16x32_bf16(af[i], bfr[j], acc[i][j], 0, 0, 0);
        __syncthreads();
    }

    const int fr = lane & 15, fq = (lane >> 4) * 4;
    #pragma unroll
    for (int i = 0; i < 4; ++i) {
        #pragma unroll
        for (int j = 0; j < 4; ++j) {
            int col = bn + wcol + j * 16 + fr;
            #pragma unroll
            for (int v = 0; v < 4; ++v) {
                int row = bm + wrow + i * 16 + fq + v;
                float d = acc[i][j][v];
                if (EPI == 1) Cf[(size_t)row * N + col] = d + bias[col];
                else          Cb[(size_t)row * N + col] = f2bf(d);
            }
        }
    }
}

// ============ 256x256 8-phase GEMM core (shared) ============
#define FENCE asm volatile("" ::: "memory")
#define BAR   do { FENCE; __builtin_amdgcn_s_barrier(); FENCE; } while (0)
#define MFMA16(I0, J0)                                                                       \
    _Pragma("unroll") for (int x = 0; x < 4; ++x)                                            \
    _Pragma("unroll") for (int y = 0; y < 2; ++y)                                            \
    _Pragma("unroll") for (int s = 0; s < 2; ++s)                                            \
        acc[(I0)+x][(J0)+y] = __builtin_amdgcn_mfma_f32_16x16x32_bf16(                       \
            af[x][s], bf[(J0)+y][s], acc[(I0)+x][(J0)+y], 0, 0, 0);

#define GEMM256_CORE(NIT, KMASK)                                                             \
    stageA(0, 0, 0); stageA(0, 1, 0);                                                        \
    stageB(0, 0, 0); stageB(0, 1, 0);                                                        \
    stageB(1, 0, 1); stageB(1, 1, 1);                                                        \
    asm volatile("s_waitcnt vmcnt(4)" ::: "memory");                                         \
    __builtin_amdgcn_s_barrier();                                                            \
    FENCE;                                                                                   \
    _Pragma("unroll 1")                                                                      \
    for (int it = 0; it < (NIT); ++it) {                                                     \
        const int kt = it * 2;                                                               \
        _Pragma("unroll") for (int x = 0; x < 4; ++x) { af[x][0] = lda(A0o, x, 0); af[x][1] = lda(A0o, x, 1); } \
        _Pragma("unroll") for (int y = 0; y < 2; ++y) { bf[y][0] = ldb(B0o, y, 0); bf[y][1] = ldb(B0o, y, 1); } \
        stageA(1, 0, kt + 1);                                                                \
        asm volatile("s_waitcnt lgkmcnt(8)" ::: "memory");                                   \
        BAR; __builtin_amdgcn_s_setprio(1); MFMA16(0, 0) __builtin_amdgcn_s_setprio(0); BAR; \
        _Pragma("unroll") for (int y = 0; y < 2; ++y) { bf[2+y][0] = ldb(B0o, 2+y, 0); bf[2+y][1] = ldb(B0o, 2+y, 1); } \
        stageA(1, 1, kt + 1);                                                                \
        BAR; __builtin_amdgcn_s_setprio(1); MFMA16(0, 2) __builtin_amdgcn_s_setprio(0); BAR; \
        _Pragma("unroll") for (int x = 0; x < 4; ++x) { af[x][0] = lda(A0o, 4+x, 0); af[x][1] = lda(A0o, 4+x, 1); } \
        stageB(0, 0, kt + 2);                                                                \
        BAR; __builtin_amdgcn_s_setprio(1); MFMA16(4, 0) __builtin_amdgcn_s_setprio(0); BAR; \
        stageB(0, 1, kt + 2);                                                                \
        BAR; __builtin_amdgcn_s_setprio(1); MFMA16(4, 2) __builtin_amdgcn_s_setprio(0);      \
        asm volatile("s_waitcnt vmcnt(4)" ::: "memory"); BAR;                                \
        _Pragma("unroll") for (int x = 0; x < 4; ++x) { af[x][0] = lda(A1o, x, 0); af[x][1] = lda(A1o, x, 1); } \
        _Pragma("unroll") for (int y = 0; y < 2; ++y) { bf[y][0] = ldb(B1o, y, 0); bf[y][1] = ldb(B1o, y, 1); } \
        stageA(0, 0, kt + 2);                                                                \
        asm volatile("s_waitcnt lgkmcnt(8)" ::: "memory");                                   \
        BAR; __builtin_amdgcn_s_setprio(1); MFMA16(0, 0) __builtin_amdgcn_s_setprio(0); BAR; \
        _Pragma("unroll") for (int y = 0; y < 2; ++y) { bf[2+y][0] = ldb(B1o, 2+y, 0); bf[2+y][1] = ldb(B1o, 2+y, 1); } \
        stageA(0, 1, kt + 2);                                                                \
        BAR; __builtin_amdgcn_s_setprio(1); MFMA16(0, 2) __builtin_amdgcn_s_setprio(0); BAR; \
        _Pragma("unroll") for (int x = 0; x < 4; ++x) { af[x][0] = lda(A1o, 4+x, 0); af[x][1] = lda(A1o, 4+x, 1); } \
        stageB(1, 0, kt + 3);                                                                \
        BAR; __builtin_amdgcn_s_setprio(1); MFMA16(4, 0) __builtin_amdgcn_s_setprio(0); BAR; \
        stageB(1, 1, kt + 3);                                                                \
        BAR; __builtin_amdgcn_s_setprio(1); MFMA16(4, 2) __builtin_amdgcn_s_setprio(0);      \
        asm volatile("s_waitcnt vmcnt(4)" ::: "memory"); BAR;                                \
    }                                                                                        \
    asm volatile("s_waitcnt vmcnt(0)" ::: "memory");                                         \
    BAR;

#define GEMM256_PRELUDE(KMASK)                                                               \
    const int tid  = threadIdx.x;                                                            \
    const int wave = tid >> 6;                                                               \
    const int lane = tid & 63;                                                               \
    const int wm = wave >> 2;                                                                \
    const int wn = wave & 3;                                                                 \
    const int fr = lane & 15;                                                                \
    const int kq = lane >> 4;                                                                \
    const int lr = lane >> 3;                                                                \
    const int lsl = (lane & 7) ^ lr;                                                         \
    const int A0o = wm * 8192;                                                               \
    const int A1o = 16384 + wm * 8192;                                                       \
    const int B0o = 32768 + ((wn >> 1) << 13);                                               \
    const int B1o = B0o + 16384;                                                             \
    const short* aSrc = A + (size_t)(bm + wave * 8 + lr) * 8192 + kb + lsl * 8;              \
    const short* bSrc = B + (size_t)(bn + wave * 8 + lr) * 8192 + kb + lsl * 8;              \
    auto stageA = [&](int buf, int h, int kt) {                                              \
        const short* s0 = aSrc + ((size_t)h << 20) + ((kt << 6) & (KMASK));                  \
        short* d = &lds[buf * 16384 + h * 8192 + wave * 512];                                \
        __builtin_amdgcn_global_load_lds((const __attribute__((address_space(1))) void*)s0,  \
            (__attribute__((address_space(3))) void*)d, 16, 0, 0);                           \
        __builtin_amdgcn_global_load_lds((const __attribute__((address_space(1))) void*)(s0 + (size_t)(64 * 8192)), \
            (__attribute__((address_space(3))) void*)(d + 4096), 16, 0, 0);                  \
    };                                                                                       \
    auto stageB = [&](int buf, int h, int kt) {                                              \
        const short* s0 = bSrc + ((size_t)h << 20) + ((kt << 6) & (KMASK));                  \
        short* d = &lds[32768 + buf * 16384 + h * 8192 + wave * 512];                        \
        __builtin_amdgcn_global_load_lds((const __attribute__((address_space(1))) void*)s0,  \
            (__attribute__((address_space(3))) void*)d, 16, 0, 0);                           \
        __builtin_amdgcn_global_load_lds((const __attribute__((address_space(1))) void*)(s0 + (size_t)(64 * 8192)), \
            (__attribute__((address_space(3))) void*)(d + 4096), 16, 0, 0);                  \
    };                                                                                       \
    auto lda = [&](int base, int i, int ks) -> s16x8 {                                       \
        int rl = i * 16 + fr;                                                                \
        int slot = ((ks << 2) + kq) ^ (rl & 7);                                              \
        return *(const s16x8*)&lds[base + rl * 64 + slot * 8];                               \
    };                                                                                       \
    auto ldb = [&](int base, int j, int ks) -> s16x8 {                                       \
        int rl = ((wn & 1) << 6) + j * 16 + fr;                                              \
        int slot = ((ks << 2) + kq) ^ (rl & 7);                                              \
        return *(const s16x8*)&lds[base + rl * 64 + slot * 8];                               \
    };                                                                                       \
    f32x4 acc[8][4] = {};                                                                    \
    s16x8 af[4][2], bf[4][2];

// ============ symmetric m1 = Tg @ Tb^T, 512 blocks (2 perfect rounds) ============
__global__ __launch_bounds__(512, 2)
void gemm256(const short* __restrict__ A, const short* __restrict__ B,
             const float* __restrict__ adj, short* __restrict__ Cb) {
    __shared__ short lds[65536];

    // XCD swizzle (512 % 8 == 0, bijective)
    int b = blockIdx.x;
    b = (b & 7) * 64 + (b >> 3);
    int bi, bj;
    if (b < 496) {                 // strictly-upper pairs
        int rem = b;
        bi = 0;
        while (rem >= 31 - bi) { rem -= 31 - bi; ++bi; }
        bj = bi + 1 + rem;
    } else {                       // diagonal tiles bi = bj in [0,16)
        bi = bj = b - 496;
    }
    const int bm = bi << 8;
    const int bn = bj << 8;
    const int kb = 0;

    GEMM256_PRELUDE(8191)
    GEMM256_CORE(64, 8191)

    // ---------- epilogue E1: acc -> lds normal swizzled [256][256] ----------
    const int fq = kq << 2;
    #pragma unroll
    for (int i = 0; i < 8; ++i) {
        int rl0 = wm * 128 + i * 16 + fq;
        #pragma unroll
        for (int j = 0; j < 4; ++j) {
            int cl = wn * 64 + j * 16 + fr;
            #pragma unroll
            for (int v = 0; v < 4; ++v) {
                int rl = rl0 + v;
                lds[rl * 256 + (cl ^ ((rl & 7) << 3))] = f2bf(acc[i][j][v]);
            }
        }
    }
    BAR;

    // ---------- E2: tile (bi,bj), coalesced ----------
    const int rloc = tid >> 5;
    const int cc   = (tid & 31) * 8;
    #pragma unroll 4
    for (int m = 0; m < 16; ++m) {
        int r = m * 16 + rloc;
        s16x8 mv = *(const s16x8*)&lds[r * 256 + (cc ^ ((r & 7) << 3))];
        const float* arow = adj + (size_t)(bm + r) * 8192 + bn + cc;
        float4 a0 = *(const float4*)arow;
        float4 a1 = *(const float4*)(arow + 4);
        float av[8] = {a0.x,a0.y,a0.z,a0.w,a1.x,a1.y,a1.z,a1.w};
        s16x8 o;
        #pragma unroll
        for (int e = 0; e < 8; ++e) {
            float cv = av[e] * (0.5f * bf2f(mv[e]) + 0.5f);
            if (bm == bn && r == cc + e) cv = av[e];
            o[e] = f2bf(cv);
        }
        *(s16x8*)&Cb[(size_t)(bm + r) * 8192 + bn + cc] = o;
    }

    // ---------- E3: mirror tile (bj,bi) via padded-transpose LDS, two halves ----------
    if (bm != bn) {
        #pragma unroll 1
        for (int h = 0; h < 2; ++h) {
            BAR;   // protect lds reuse (E2 reads / previous half reads done)
            if ((wn >> 1) == h) {
                // scatter acc cols [h*128, h*128+128) -> ldsT[c][r], stride 264 (pad 8)
                // 4 row-consecutive acc values pack into one ds_write_b64
                #pragma unroll
                for (int i = 0; i < 8; ++i) {
                    int r0 = wm * 128 + i * 16 + fq;
                    #pragma unroll
                    for (int j = 0; j < 4; ++j) {
                        int c = ((wn & 1) << 6) + j * 16 + fr;
                        s16x4 o4;
                        o4[0] = f2bf(acc[i][j][0]); o4[1] = f2bf(acc[i][j][1]);
                        o4[2] = f2bf(acc[i][j][2]); o4[3] = f2bf(acc[i][j][3]);
                        *(s16x4*)&lds[c * 264 + r0] = o4;
                    }
                }
            }
            BAR;
            // coalesced: thread reads 16B rows of ldsT, writes mirror rows of Cb
            const int r0 = (tid & 31) * 8;
            #pragma unroll 2
            for (int itr = 0; itr < 8; ++itr) {
                int c = itr * 16 + (tid >> 5);
                s16x8 mv = *(const s16x8*)&lds[c * 264 + r0];
                const float* arow = adj + (size_t)(bn + h * 128 + c) * 8192 + bm + r0;
                float4 a0 = *(const float4*)arow;
                float4 a1 = *(const float4*)(arow + 4);
                float av[8] = {a0.x,a0.y,a0.z,a0.w,a1.x,a1.y,a1.z,a1.w};
                s16x8 o;
                #pragma unroll
                for (int e = 0; e < 8; ++e)
                    o[e] = f2bf(av[e] * (0.5f * bf2f(mv[e]) + 0.5f));
                *(s16x8*)&Cb[(size_t)(bn + h * 128 + c) * 8192 + bm + r0] = o;
            }
        }
    }
}

// K-split variant: 16 diagonal tiles (bi in [16,32)) x 16 K-slices of 512.
__global__ __launch_bounds__(512, 2)
void gemm256_ks(const short* __restrict__ A, const short* __restrict__ B,
                float* __restrict__ part) {
    __shared__ short lds[65536];

    int b = blockIdx.x;            // 256 blocks
    const int t  = b >> 4;         // 0..15
    const int ks = b & 15;         // K-slice
    const int bm = (16 + t) << 8;
    const int bn = bm;
    const int kb = ks << 9;        // 512-col slice base

    GEMM256_PRELUDE(511)
    GEMM256_CORE(4, 511)

    float* po = part + (size_t)(t * 16 + ks) * 65536;
    const int fq = kq << 2;
    #pragma unroll
    for (int i = 0; i < 8; ++i) {
        #pragma unroll
        for (int j = 0; j < 4; ++j) {
            int C = wn * 64 + j * 16 + fr;
            #pragma unroll
            for (int v = 0; v < 4; ++v) {
                int R = wm * 128 + i * 16 + fq + v;
                po[R * 256 + C] = acc[i][j][v];
            }
        }
    }
}

// Sum 16 partials per diagonal tile + adj epilogue -> Cb
__global__ void reduce_diag(const float* __restrict__ part, const float* __restrict__ adj,
                            short* __restrict__ Cb) {
    int b = blockIdx.x;            // 512 = 16 tiles x 32 sub-blocks
    int t = b >> 5, sub = b & 31;
    int base = sub * 2048 + threadIdx.x * 8;
    int r = base >> 8, c = base & 255;
    const float* ps = part + (size_t)t * 16 * 65536 + base;
    float s[8] = {};
    #pragma unroll
    for (int ks = 0; ks < 16; ++ks) {
        f32x4 a = *(const f32x4*)(ps + (size_t)ks * 65536);
        f32x4 bq = *(const f32x4*)(ps + (size_t)ks * 65536 + 4);
        s[0]+=a[0]; s[1]+=a[1]; s[2]+=a[2]; s[3]+=a[3];
        s[4]+=bq[0]; s[5]+=bq[1]; s[6]+=bq[2]; s[7]+=bq[3];
    }
    int gr = (16 + t) * 256 + r, gc0 = (16 + t) * 256 + c;
    const float* arow = adj + (size_t)gr * 8192 + gc0;
    float4 a0 = *(const float4*)arow, a1 = *(const float4*)(arow + 4);
    float av[8] = {a0.x,a0.y,a0.z,a0.w,a1.x,a1.y,a1.z,a1.w};
    s16x8 o;
    #pragma unroll
    for (int e = 0; e < 8; ++e) {
        float cv = av[e] * (0.5f * s[e] + 0.5f);
        if (gr == gc0 + e) cv = av[e];
        o[e] = f2bf(cv);
    }
    *(s16x8*)&Cb[(size_t)gr * 8192 + gc0] = o;
}

// ============ final GEMM out = Cb @ Wt^T, 256^2 tiles, 4-way K-split ============
// 64 tiles (32 bm x 2 bn) x 4 K-slices of 2048 = 256 blocks = 1 machine round.
// b = bn*128 + bm*4 + ks  (bn-pair 128 apart -> same XCD -> shared A panel in L2)
__global__ __launch_bounds__(512, 2)
void gemm_fin(const short* __restrict__ A, const short* __restrict__ B,
              float* __restrict__ part) {
    __shared__ short lds[65536];

    int b = blockIdx.x;            // 256 blocks
    const int ks  = b & 3;
    const int bmi = (b >> 2) & 31;
    const int bni = b >> 7;
    const int bm = bmi << 8;
    const int bn = bni << 8;
    const int kb = ks << 11;       // 2048-col slice base

    GEMM256_PRELUDE(2047)
    GEMM256_CORE(16, 2047)

    float* po = part + ((size_t)(bmi * 2 + bni) * 4 + ks) * 65536;
    const int fq = kq << 2;
    #pragma unroll
    for (int i = 0; i < 8; ++i) {
        #pragma unroll
        for (int j = 0; j < 4; ++j) {
            int C = wn * 64 + j * 16 + fr;
            #pragma unroll
            for (int v = 0; v < 4; ++v) {
                int R = wm * 128 + i * 16 + fq + v;
                po[R * 256 + C] = acc[i][j][v];
            }
        }
    }
}

// out[r][c] = sum_ks part[tile][ks][...] + bias[c]   (f32, coalesced)
__global__ void reduce_out(const float* __restrict__ part, const float* __restrict__ bias,
                           float* __restrict__ out) {
    size_t g = ((size_t)blockIdx.x * 256 + threadIdx.x) * 8;   // over 8192*512
    int r = (int)(g >> 9);
    int c = (int)(g & 511);
    int tile = ((r >> 8) << 1) + (c >> 8);
    size_t inner = (size_t)(r & 255) * 256 + (c & 255);
    const float* ps = part + ((size_t)tile * 4) * 65536 + inner;
    float s[8] = {};
    #pragma unroll
    for (int ks = 0; ks < 4; ++ks) {
        f32x4 a = *(const f32x4*)(ps + (size_t)ks * 65536);
        f32x4 bq = *(const f32x4*)(ps + (size_t)ks * 65536 + 4);
        s[0]+=a[0]; s[1]+=a[1]; s[2]+=a[2]; s[3]+=a[3];
        s[4]+=bq[0]; s[5]+=bq[1]; s[6]+=bq[2]; s[7]+=bq[3];
    }
    float4 b0 = *(const float4*)(bias + c);
    float4 b1 = *(const float4*)(bias + c + 4);
    float bv[8] = {b0.x,b0.y,b0.z,b0.w,b1.x,b1.y,b1.z,b1.w};
    f32x4 o0, o1;
    o0[0]=s[0]+bv[0]; o0[1]=s[1]+bv[1]; o0[2]=s[2]+bv[2]; o0[3]=s[3]+bv[3];
    o1[0]=s[4]+bv[4]; o1[1]=s[5]+bv[5]; o1[2]=s[6]+bv[6]; o1[3]=s[7]+bv[7];
    *(f32x4*)(out + g) = o0;
    *(f32x4*)(out + g + 4) = o1;
}

extern "C" void kernel_launch(void* const* d_in, const int* in_sizes, int n_in,
                              void* d_out, int out_size, void* d_ws, size_t ws_size,
                              hipStream_t stream) {
    const float* Hv   = (const float*)d_in[0];
    const float* He   = (const float*)d_in[1];
    // d_in[2] = adj_e (unused by the reference)
    const float* adjv = (const float*)d_in[3];
    const float* T    = (const float*)d_in[4];
    const float* Wf   = (const float*)d_in[5];
    const float* p    = (const float*)d_in[6];
    const float* bias = (const float*)d_in[7];
    float* out = (float*)d_out;

    char* ws = (char*)d_ws;
    float* gate = (float*)(ws);                      //   32 KB
    short* Hvb  = (short*)(ws + 32768);              //    8 MB
    short* Wt   = (short*)(ws + 8421376);            //    8 MB  (HW^T, [512][8192])
    short* Tg   = (short*)(ws + 16809984);           //  128 MB
    short* Tb   = (short*)(ws + 151027712);          //  128 MB
    short* Cb   = (short*)(ws + 285245440);          //  128 MB
    short* WTb  = (short*)(ws + 285245440);          // aliased with Cb (consumed early)
    // diag partials (64 MB): alias Tg[0:64MB] — gemm256_ks only READS Tg rows >= 4096
    float* part = (float*)(ws + 16809984);
    // final-GEMM partials (64 MB): same region, used after Tg is fully dead
    float* part2 = (float*)(ws + 16809984);

    // second tuple output: H_e passthrough
    hipMemcpyAsync(out + (size_t)NV * DIM, He, (size_t)NE * DIM * sizeof(float),
                   hipMemcpyDeviceToDevice, stream);

    gate_kernel<<<NE / 4, 256, 0, stream>>>(He, p, gate);
    convert_T<<<(NV * (NE / 8)) / 256, 256, 0, stream>>>(T, gate, Tg, Tb);
    to_bf16<<<(NV * DIM / 8) / 256, 256, 0, stream>>>(Hv, Hvb);
    wT_bf16<<<dim3(8, 8), 256, 0, stream>>>(Wf, WTb);

    // Wt[j][k] = sum_c WT[j][c] * Hvb[k][c] = (Hv@W)^T   (M=512, N=8192, K=512)
    gemm_bt<2><<<(DIM / 128) * (NV / 128), 256, 0, stream>>>(
        WTb, Hvb, DIM, NV, DIM, Wt, nullptr, nullptr);

    // C = 0.5*adjusted_A + 0.5*adj_v fused into (Tg @ Tb^T), symmetric-triangular:
    // 496 upper tiles + 16 diag (bi<16) = 512 blocks (2 perfect machine rounds)
    gemm256<<<512, 512, 0, stream>>>(Tg, Tb, adjv, Cb);
    // remaining 16 diag tiles (bi>=16) as 16-way K-split (1 full round)
    gemm256_ks<<<256, 512, 0, stream>>>(Tg, Tb, part);
    reduce_diag<<<512, 256, 0, stream>>>(part, adjv, Cb);

    // out = C @ HW + bias: 256^2-tile 8-phase, 4-way K-split (1 round) + reduce
    gemm_fin<<<256, 512, 0, stream>>>(Cb, Wt, part2);
    reduce_out<<<(NV * DIM / 8) / 256, 256, 0, stream>>>(part2, bias, out);
}

// Round 8
// 722.564 us; speedup vs baseline: 1.0046x; 1.0046x over previous
//
#include <hip/hip_runtime.h>
#include <hip/hip_bf16.h>

typedef __attribute__((ext_vector_type(4))) float  f32x4;
typedef __attribute__((ext_vector_type(8))) short  s16x8;
typedef __attribute__((ext_vector_type(4))) short  s16x4;

#define NV 8192
#define NE 8192
#define DIM 512

__device__ inline short f2bf(float x) {
    unsigned u = __float_as_uint(x);
    u += 0x7fffu + ((u >> 16) & 1u);   // round-to-nearest-even
    return (short)(u >> 16);
}
__device__ inline float bf2f(short s) {
    return __uint_as_float(((unsigned)(unsigned short)s) << 16);
}

// ---------------- gate[e] = sum_c H_e[e,c] * p[c] ----------------
__global__ void gate_kernel(const float* __restrict__ He, const float* __restrict__ p,
                            float* __restrict__ gate) {
    int row  = blockIdx.x * 4 + (threadIdx.x >> 6);
    int lane = threadIdx.x & 63;
    const float* r = He + (size_t)row * DIM + lane * 8;
    float4 a0 = *(const float4*)r;
    float4 a1 = *(const float4*)(r + 4);
    float4 p0 = *(const float4*)(p + lane * 8);
    float4 p1 = *(const float4*)(p + lane * 8 + 4);
    float s = a0.x*p0.x + a0.y*p0.y + a0.z*p0.z + a0.w*p0.w
            + a1.x*p1.x + a1.y*p1.y + a1.z*p1.z + a1.w*p1.w;
    #pragma unroll
    for (int off = 32; off; off >>= 1) s += __shfl_down(s, off);
    if (lane == 0) gate[row] = s;
}

// ------------- Tg = bf16(T * gate[col]), Tb = bf16(T) -------------
__global__ void convert_T(const float* __restrict__ T, const float* __restrict__ gate,
                          short* __restrict__ Tg, short* __restrict__ Tb) {
    size_t gid  = (size_t)blockIdx.x * blockDim.x + threadIdx.x;
    size_t base = gid * 8;
    int col = (int)(base & (NE - 1));
    float4 t0 = *(const float4*)(T + base);
    float4 t1 = *(const float4*)(T + base + 4);
    float4 g0 = *(const float4*)(gate + col);
    float4 g1 = *(const float4*)(gate + col + 4);
    s16x8 vb, vg;
    vb[0]=f2bf(t0.x); vb[1]=f2bf(t0.y); vb[2]=f2bf(t0.z); vb[3]=f2bf(t0.w);
    vb[4]=f2bf(t1.x); vb[5]=f2bf(t1.y); vb[6]=f2bf(t1.z); vb[7]=f2bf(t1.w);
    vg[0]=f2bf(t0.x*g0.x); vg[1]=f2bf(t0.y*g0.y); vg[2]=f2bf(t0.z*g0.z); vg[3]=f2bf(t0.w*g0.w);
    vg[4]=f2bf(t1.x*g1.x); vg[5]=f2bf(t1.y*g1.y); vg[6]=f2bf(t1.z*g1.z); vg[7]=f2bf(t1.w*g1.w);
    *(s16x8*)(Tb + base) = vb;
    *(s16x8*)(Tg + base) = vg;
}

// ------------- f32 -> bf16 bulk convert -------------
__global__ void to_bf16(const float* __restrict__ in, short* __restrict__ out) {
    size_t base = ((size_t)blockIdx.x * blockDim.x + threadIdx.x) * 8;
    float4 a = *(const float4*)(in + base);
    float4 b = *(const float4*)(in + base + 4);
    s16x8 v;
    v[0]=f2bf(a.x); v[1]=f2bf(a.y); v[2]=f2bf(a.z); v[3]=f2bf(a.w);
    v[4]=f2bf(b.x); v[5]=f2bf(b.y); v[6]=f2bf(b.z); v[7]=f2bf(b.w);
    *(s16x8*)(out + base) = v;
}

// ------------- WT[c][r] = bf16(W[r][c])  (512x512 transpose-convert) -------------
__global__ void wT_bf16(const float* __restrict__ W, short* __restrict__ WT) {
    __shared__ short t[64][65];
    int rb = blockIdx.x, cb = blockIdx.y;
    int c = threadIdx.x & 63, r0 = threadIdx.x >> 6;
    #pragma unroll
    for (int i = 0; i < 16; ++i) {
        int r = i * 4 + r0;
        t[r][c] = f2bf(W[(size_t)(rb * 64 + r) * DIM + cb * 64 + c]);
    }
    __syncthreads();
    #pragma unroll
    for (int i = 0; i < 16; ++i) {
        int r = i * 4 + r0;
        WT[(size_t)(cb * 64 + r) * DIM + rb * 64 + c] = t[c][r];
    }
}

// ------------- B^T GEMM (128x128 tile) for the small GEMMs -------------
template<int EPI>
__global__ __launch_bounds__(256)
void gemm_bt(const short* __restrict__ A, const short* __restrict__ B,
             int M, int N, int K,
             short* __restrict__ Cb,
             const float* __restrict__ bias, float* __restrict__ Cf) {
    __shared__ short As[128 * 32];
    __shared__ short Bs[128 * 32];

    int nwg = gridDim.x;
    int bid = blockIdx.x;
    int cpx = nwg >> 3;
    bid = (bid & 7) * cpx + (bid >> 3);

    const int nbn = N >> 7;
    const int bm = (bid / nbn) << 7;
    const int bn = (bid % nbn) << 7;
    const int tid  = threadIdx.x;
    const int lane = tid & 63;
    const int wave = tid >> 6;
    const int wrow = (wave >> 1) * 64;
    const int wcol = (wave & 1) * 64;

    f32x4 acc[4][4] = {};

    const int lrow = lane >> 2;
    const int lcol = ((lane & 3) ^ ((lrow >> 1) & 3)) * 8;   // inverse-swizzled source slot

    for (int k0 = 0; k0 < K; k0 += 32) {
        #pragma unroll
        for (int it = 0; it < 2; ++it) {
            int chunk = it * 4 + wave;
            int row = chunk * 16 + lrow;
            __builtin_amdgcn_global_load_lds(
                (const __attribute__((address_space(1))) void*)(A + (size_t)(bm + row) * K + k0 + lcol),
                (__attribute__((address_space(3))) void*)(As + chunk * 512), 16, 0, 0);
            __builtin_amdgcn_global_load_lds(
                (const __attribute__((address_space(1))) void*)(B + (size_t)(bn + row) * K + k0 + lcol),
                (__attribute__((address_space(3))) void*)(Bs + chunk * 512), 16, 0, 0);
        }
        __syncthreads();

        const int fr = lane & 15;
        const int sw = (fr >> 1) & 3;
        const int sa = ((lane >> 4) ^ sw) * 8;               // swizzled read slot
        s16x8 af[4], bfr[4];
        #pragma unroll
        for (int i = 0; i < 4; ++i) {
            af[i]  = *(const s16x8*)&As[(wrow + i * 16 + fr) * 32 + sa];
            bfr[i] = *(const s16x8*)&Bs[(wcol + i * 16 + fr) * 32 + sa];
        }
        #pragma unroll
        for (int i = 0; i < 4; ++i)
            #pragma unroll
            for (int j = 0; j < 4; ++j)
                acc[i][j] = __builtin_amdgcn_mfma_f32_16x16x32_bf16(af[i], bfr[j], acc[i][j], 0, 0, 0);
        __syncthreads();
    }

    const int fr = lane & 15, fq = (lane >> 4) * 4;
    #pragma unroll
    for (int i = 0; i < 4; ++i) {
        #pragma unroll
        for (int j = 0; j < 4; ++j) {
            int col = bn + wcol + j * 16 + fr;
            #pragma unroll
            for (int v = 0; v < 4; ++v) {
                int row = bm + wrow + i * 16 + fq + v;
                float d = acc[i][j][v];
                if (EPI == 1) Cf[(size_t)row * N + col] = d + bias[col];
                else          Cb[(size_t)row * N + col] = f2bf(d);
            }
        }
    }
}

// ============ 256x256 8-phase GEMM core (shared) ============
// LDS 160 KiB: A triple-buffered K-tiles (slots @0/16384/32768 shorts, 32 KiB each),
// B double-buffered (@49152/65536). A slots rotate by 2 K-tiles per iteration:
// reads kt from cA, kt+1 from cB; stages kt+2 -> cC (ph1/2), kt+3 -> cA (ph5/6).
// Every half-tile gets 7-8 phases in flight; vmcnt(8) at ph4/ph8 forces only the
// 8 oldest loads (issued a full iteration earlier) -> no latency stall.
#define FENCE asm volatile("" ::: "memory")
#define BAR   do { FENCE; __builtin_amdgcn_s_barrier(); FENCE; } while (0)
#define MFMA16(I0, J0)                                                                       \
    _Pragma("unroll") for (int x = 0; x < 4; ++x)                                            \
    _Pragma("unroll") for (int y = 0; y < 2; ++y)                                            \
    _Pragma("unroll") for (int s = 0; s < 2; ++s)                                            \
        acc[(I0)+x][(J0)+y] = __builtin_amdgcn_mfma_f32_16x16x32_bf16(                       \
            af[x][s], bf[(J0)+y][s], acc[(I0)+x][(J0)+y], 0, 0, 0);

#define GEMM256_CORE(NIT, KMASK)                                                             \
    int cA = 0, cB = 16384, cC = 32768;                                                      \
    stageA(0, 0, 0); stageA(0, 1, 0);                                                        \
    stageB(0, 0, 0); stageB(0, 1, 0);                                                        \
    stageA(16384, 0, 1); stageA(16384, 1, 1);                                                \
    stageB(1, 0, 1); stageB(1, 1, 1);                                                        \
    asm volatile("s_waitcnt vmcnt(8)" ::: "memory");                                         \
    __builtin_amdgcn_s_barrier();                                                            \
    FENCE;                                                                                   \
    _Pragma("unroll 1")                                                                      \
    for (int it = 0; it < (NIT); ++it) {                                                     \
        const int kt = it * 2;                                                               \
        _Pragma("unroll") for (int x = 0; x < 4; ++x) { af[x][0] = lda(cA, x, 0); af[x][1] = lda(cA, x, 1); } \
        _Pragma("unroll") for (int y = 0; y < 2; ++y) { bf[y][0] = ldb(B0o, y, 0); bf[y][1] = ldb(B0o, y, 1); } \
        stageA(cC, 0, kt + 2);                                                               \
        asm volatile("s_waitcnt lgkmcnt(8)" ::: "memory");                                   \
        BAR; __builtin_amdgcn_s_setprio(1); MFMA16(0, 0) __builtin_amdgcn_s_setprio(0); BAR; \
        _Pragma("unroll") for (int y = 0; y < 2; ++y) { bf[2+y][0] = ldb(B0o, 2+y, 0); bf[2+y][1] = ldb(B0o, 2+y, 1); } \
        stageA(cC, 1, kt + 2);                                                               \
        BAR; __builtin_amdgcn_s_setprio(1); MFMA16(0, 2) __builtin_amdgcn_s_setprio(0); BAR; \
        _Pragma("unroll") for (int x = 0; x < 4; ++x) { af[x][0] = lda(cA, 4+x, 0); af[x][1] = lda(cA, 4+x, 1); } \
        stageB(0, 0, kt + 2);                                                                \
        BAR; __builtin_amdgcn_s_setprio(1); MFMA16(4, 0) __builtin_amdgcn_s_setprio(0); BAR; \
        stageB(0, 1, kt + 2);                                                                \
        BAR; __builtin_amdgcn_s_setprio(1); MFMA16(4, 2) __builtin_amdgcn_s_setprio(0);      \
        asm volatile("s_waitcnt vmcnt(8)" ::: "memory"); BAR;                                \
        _Pragma("unroll") for (int x = 0; x < 4; ++x) { af[x][0] = lda(cB, x, 0); af[x][1] = lda(cB, x, 1); } \
        _Pragma("unroll") for (int y = 0; y < 2; ++y) { bf[y][0] = ldb(B1o, y, 0); bf[y][1] = ldb(B1o, y, 1); } \
        stageA(cA, 0, kt + 3);                                                               \
        asm volatile("s_waitcnt lgkmcnt(8)" ::: "memory");                                   \
        BAR; __builtin_amdgcn_s_setprio(1); MFMA16(0, 0) __builtin_amdgcn_s_setprio(0); BAR; \
        _Pragma("unroll") for (int y = 0; y < 2; ++y) { bf[2+y][0] = ldb(B1o, 2+y, 0); bf[2+y][1] = ldb(B1o, 2+y, 1); } \
        stageA(cA, 1, kt + 3);                                                               \
        BAR; __builtin_amdgcn_s_setprio(1); MFMA16(0, 2) __builtin_amdgcn_s_setprio(0); BAR; \
        _Pragma("unroll") for (int x = 0; x < 4; ++x) { af[x][0] = lda(cB, 4+x, 0); af[x][1] = lda(cB, 4+x, 1); } \
        stageB(1, 0, kt + 3);                                                                \
        BAR; __builtin_amdgcn_s_setprio(1); MFMA16(4, 0) __builtin_amdgcn_s_setprio(0); BAR; \
        stageB(1, 1, kt + 3);                                                                \
        BAR; __builtin_amdgcn_s_setprio(1); MFMA16(4, 2) __builtin_amdgcn_s_setprio(0);      \
        asm volatile("s_waitcnt vmcnt(8)" ::: "memory"); BAR;                                \
        int tRot = cA; cA = cC; cC = cB; cB = tRot;                                          \
    }                                                                                        \
    asm volatile("s_waitcnt vmcnt(0)" ::: "memory");                                         \
    BAR;

#define GEMM256_PRELUDE(KMASK)                                                               \
    const int tid  = threadIdx.x;                                                            \
    const int wave = tid >> 6;                                                               \
    const int lane = tid & 63;                                                               \
    const int wm = wave >> 2;                                                                \
    const int wn = wave & 3;                                                                 \
    const int fr = lane & 15;                                                                \
    const int kq = lane >> 4;                                                                \
    const int lr = lane >> 3;                                                                \
    const int lsl = (lane & 7) ^ lr;                                                         \
    const int awm = wm * 8192;                                                               \
    const int B0o = 49152 + ((wn >> 1) << 13);                                               \
    const int B1o = B0o + 16384;                                                             \
    const short* aSrc = A + (size_t)(bm + wave * 8 + lr) * 8192 + kb + lsl * 8;              \
    const short* bSrc = B + (size_t)(bn + wave * 8 + lr) * 8192 + kb + lsl * 8;              \
    auto stageA = [&](int slotBase, int h, int kt) {                                         \
        const short* s0 = aSrc + ((size_t)h << 20) + ((kt << 6) & (KMASK));                  \
        short* d = &lds[slotBase + h * 8192 + wave * 512];                                   \
        __builtin_amdgcn_global_load_lds((const __attribute__((address_space(1))) void*)s0,  \
            (__attribute__((address_space(3))) void*)d, 16, 0, 0);                           \
        __builtin_amdgcn_global_load_lds((const __attribute__((address_space(1))) void*)(s0 + (size_t)(64 * 8192)), \
            (__attribute__((address_space(3))) void*)(d + 4096), 16, 0, 0);                  \
    };                                                                                       \
    auto stageB = [&](int buf, int h, int kt) {                                              \
        const short* s0 = bSrc + ((size_t)h << 20) + ((kt << 6) & (KMASK));                  \
        short* d = &lds[49152 + buf * 16384 + h * 8192 + wave * 512];                        \
        __builtin_amdgcn_global_load_lds((const __attribute__((address_space(1))) void*)s0,  \
            (__attribute__((address_space(3))) void*)d, 16, 0, 0);                           \
        __builtin_amdgcn_global_load_lds((const __attribute__((address_space(1))) void*)(s0 + (size_t)(64 * 8192)), \
            (__attribute__((address_space(3))) void*)(d + 4096), 16, 0, 0);                  \
    };                                                                                       \
    auto lda = [&](int cbase, int i, int ks) -> s16x8 {                                      \
        int rl = i * 16 + fr;                                                                \
        int slot = ((ks << 2) + kq) ^ (rl & 7);                                              \
        return *(const s16x8*)&lds[cbase + awm + rl * 64 + slot * 8];                        \
    };                                                                                       \
    auto ldb = [&](int base, int j, int ks) -> s16x8 {                                       \
        int rl = ((wn & 1) << 6) + j * 16 + fr;                                              \
        int slot = ((ks << 2) + kq) ^ (rl & 7);                                              \
        return *(const s16x8*)&lds[base + rl * 64 + slot * 8];                               \
    };                                                                                       \
    f32x4 acc[8][4] = {};                                                                    \
    s16x8 af[4][2], bf[4][2];

// ============ symmetric m1 = Tg @ Tb^T, 512 blocks (2 perfect rounds) ============
__global__ __launch_bounds__(512, 2)
void gemm256(const short* __restrict__ A, const short* __restrict__ B,
             const float* __restrict__ adj, short* __restrict__ Cb) {
    __shared__ short lds[81920];   // 160 KiB

    // XCD swizzle (512 % 8 == 0, bijective)
    int b = blockIdx.x;
    b = (b & 7) * 64 + (b >> 3);
    int bi, bj;
    if (b < 496) {                 // strictly-upper pairs
        int rem = b;
        bi = 0;
        while (rem >= 31 - bi) { rem -= 31 - bi; ++bi; }
        bj = bi + 1 + rem;
    } else {                       // diagonal tiles bi = bj in [0,16)
        bi = bj = b - 496;
    }
    const int bm = bi << 8;
    const int bn = bj << 8;
    const int kb = 0;

    GEMM256_PRELUDE(8191)
    GEMM256_CORE(64, 8191)

    // ---------- epilogue E1: acc -> lds normal swizzled [256][256] ----------
    const int fq = kq << 2;
    #pragma unroll
    for (int i = 0; i < 8; ++i) {
        int rl0 = wm * 128 + i * 16 + fq;
        #pragma unroll
        for (int j = 0; j < 4; ++j) {
            int cl = wn * 64 + j * 16 + fr;
            #pragma unroll
            for (int v = 0; v < 4; ++v) {
                int rl = rl0 + v;
                lds[rl * 256 + (cl ^ ((rl & 7) << 3))] = f2bf(acc[i][j][v]);
            }
        }
    }
    BAR;

    // ---------- E2: tile (bi,bj), coalesced ----------
    const int rloc = tid >> 5;
    const int cc   = (tid & 31) * 8;
    #pragma unroll 4
    for (int m = 0; m < 16; ++m) {
        int r = m * 16 + rloc;
        s16x8 mv = *(const s16x8*)&lds[r * 256 + (cc ^ ((r & 7) << 3))];
        const float* arow = adj + (size_t)(bm + r) * 8192 + bn + cc;
        float4 a0 = *(const float4*)arow;
        float4 a1 = *(const float4*)(arow + 4);
        float av[8] = {a0.x,a0.y,a0.z,a0.w,a1.x,a1.y,a1.z,a1.w};
        s16x8 o;
        #pragma unroll
        for (int e = 0; e < 8; ++e) {
            float cv = av[e] * (0.5f * bf2f(mv[e]) + 0.5f);
            if (bm == bn && r == cc + e) cv = av[e];
            o[e] = f2bf(cv);
        }
        *(s16x8*)&Cb[(size_t)(bm + r) * 8192 + bn + cc] = o;
    }

    // ---------- E3: mirror tile (bj,bi) via padded-transpose LDS, two halves ----------
    if (bm != bn) {
        #pragma unroll 1
        for (int h = 0; h < 2; ++h) {
            BAR;   // protect lds reuse (E2 reads / previous half reads done)
            if ((wn >> 1) == h) {
                // scatter acc cols [h*128, h*128+128) -> ldsT[c][r], stride 264 (pad 8)
                #pragma unroll
                for (int i = 0; i < 8; ++i) {
                    int r0 = wm * 128 + i * 16 + fq;
                    #pragma unroll
                    for (int j = 0; j < 4; ++j) {
                        int c = ((wn & 1) << 6) + j * 16 + fr;
                        s16x4 o4;
                        o4[0] = f2bf(acc[i][j][0]); o4[1] = f2bf(acc[i][j][1]);
                        o4[2] = f2bf(acc[i][j][2]); o4[3] = f2bf(acc[i][j][3]);
                        *(s16x4*)&lds[c * 264 + r0] = o4;
                    }
                }
            }
            BAR;
            // coalesced: thread reads 16B rows of ldsT, writes mirror rows of Cb
            const int r0 = (tid & 31) * 8;
            #pragma unroll 2
            for (int itr = 0; itr < 8; ++itr) {
                int c = itr * 16 + (tid >> 5);
                s16x8 mv = *(const s16x8*)&lds[c * 264 + r0];
                const float* arow = adj + (size_t)(bn + h * 128 + c) * 8192 + bm + r0;
                float4 a0 = *(const float4*)arow;
                float4 a1 = *(const float4*)(arow + 4);
                float av[8] = {a0.x,a0.y,a0.z,a0.w,a1.x,a1.y,a1.z,a1.w};
                s16x8 o;
                #pragma unroll
                for (int e = 0; e < 8; ++e)
                    o[e] = f2bf(av[e] * (0.5f * bf2f(mv[e]) + 0.5f));
                *(s16x8*)&Cb[(size_t)(bn + h * 128 + c) * 8192 + bm + r0] = o;
            }
        }
    }
}

// K-split variant: 16 diagonal tiles (bi in [16,32)) x 16 K-slices of 512.
__global__ __launch_bounds__(512, 2)
void gemm256_ks(const short* __restrict__ A, const short* __restrict__ B,
                float* __restrict__ part) {
    __shared__ short lds[81920];

    int b = blockIdx.x;            // 256 blocks
    const int t  = b >> 4;         // 0..15
    const int ks = b & 15;         // K-slice
    const int bm = (16 + t) << 8;
    const int bn = bm;
    const int kb = ks << 9;        // 512-col slice base

    GEMM256_PRELUDE(511)
    GEMM256_CORE(4, 511)

    float* po = part + (size_t)(t * 16 + ks) * 65536;
    const int fq = kq << 2;
    #pragma unroll
    for (int i = 0; i < 8; ++i) {
        #pragma unroll
        for (int j = 0; j < 4; ++j) {
            int C = wn * 64 + j * 16 + fr;
            #pragma unroll
            for (int v = 0; v < 4; ++v) {
                int R = wm * 128 + i * 16 + fq + v;
                po[R * 256 + C] = acc[i][j][v];
            }
        }
    }
}

// Sum 16 partials per diagonal tile + adj epilogue -> Cb
__global__ void reduce_diag(const float* __restrict__ part, const float* __restrict__ adj,
                            short* __restrict__ Cb) {
    int b = blockIdx.x;            // 512 = 16 tiles x 32 sub-blocks
    int t = b >> 5, sub = b & 31;
    int base = sub * 2048 + threadIdx.x * 8;
    int r = base >> 8, c = base & 255;
    const float* ps = part + (size_t)t * 16 * 65536 + base;
    float s[8] = {};
    #pragma unroll
    for (int ks = 0; ks < 16; ++ks) {
        f32x4 a = *(const f32x4*)(ps + (size_t)ks * 65536);
        f32x4 bq = *(const f32x4*)(ps + (size_t)ks * 65536 + 4);
        s[0]+=a[0]; s[1]+=a[1]; s[2]+=a[2]; s[3]+=a[3];
        s[4]+=bq[0]; s[5]+=bq[1]; s[6]+=bq[2]; s[7]+=bq[3];
    }
    int gr = (16 + t) * 256 + r, gc0 = (16 + t) * 256 + c;
    const float* arow = adj + (size_t)gr * 8192 + gc0;
    float4 a0 = *(const float4*)arow, a1 = *(const float4*)(arow + 4);
    float av[8] = {a0.x,a0.y,a0.z,a0.w,a1.x,a1.y,a1.z,a1.w};
    s16x8 o;
    #pragma unroll
    for (int e = 0; e < 8; ++e) {
        float cv = av[e] * (0.5f * s[e] + 0.5f);
        if (gr == gc0 + e) cv = av[e];
        o[e] = f2bf(cv);
    }
    *(s16x8*)&Cb[(size_t)gr * 8192 + gc0] = o;
}

// ============ final GEMM out = Cb @ Wt^T, 256^2 tiles, 4-way K-split ============
__global__ __launch_bounds__(512, 2)
void gemm_fin(const short* __restrict__ A, const short* __restrict__ B,
              float* __restrict__ part) {
    __shared__ short lds[81920];

    int b = blockIdx.x;            // 256 blocks
    const int ks  = b & 3;
    const int bmi = (b >> 2) & 31;
    const int bni = b >> 7;
    const int bm = bmi << 8;
    const int bn = bni << 8;
    const int kb = ks << 11;       // 2048-col slice base

    GEMM256_PRELUDE(2047)
    GEMM256_CORE(16, 2047)

    float* po = part + ((size_t)(bmi * 2 + bni) * 4 + ks) * 65536;
    const int fq = kq << 2;
    #pragma unroll
    for (int i = 0; i < 8; ++i) {
        #pragma unroll
        for (int j = 0; j < 4; ++j) {
            int C = wn * 64 + j * 16 + fr;
            #pragma unroll
            for (int v = 0; v < 4; ++v) {
                int R = wm * 128 + i * 16 + fq + v;
                po[R * 256 + C] = acc[i][j][v];
            }
        }
    }
}

// out[r][c] = sum_ks part[tile][ks][...] + bias[c]   (f32, coalesced)
__global__ void reduce_out(const float* __restrict__ part, const float* __restrict__ bias,
                           float* __restrict__ out) {
    size_t g = ((size_t)blockIdx.x * 256 + threadIdx.x) * 8;   // over 8192*512
    int r = (int)(g >> 9);
    int c = (int)(g & 511);
    int tile = ((r >> 8) << 1) + (c >> 8);
    size_t inner = (size_t)(r & 255) * 256 + (c & 255);
    const float* ps = part + ((size_t)tile * 4) * 65536 + inner;
    float s[8] = {};
    #pragma unroll
    for (int ks = 0; ks < 4; ++ks) {
        f32x4 a = *(const f32x4*)(ps + (size_t)ks * 65536);
        f32x4 bq = *(const f32x4*)(ps + (size_t)ks * 65536 + 4);
        s[0]+=a[0]; s[1]+=a[1]; s[2]+=a[2]; s[3]+=a[3];
        s[4]+=bq[0]; s[5]+=bq[1]; s[6]+=bq[2]; s[7]+=bq[3];
    }
    float4 b0 = *(const float4*)(bias + c);
    float4 b1 = *(const float4*)(bias + c + 4);
    float bv[8] = {b0.x,b0.y,b0.z,b0.w,b1.x,b1.y,b1.z,b1.w};
    f32x4 o0, o1;
    o0[0]=s[0]+bv[0]; o0[1]=s[1]+bv[1]; o0[2]=s[2]+bv[2]; o0[3]=s[3]+bv[3];
    o1[0]=s[4]+bv[4]; o1[1]=s[5]+bv[5]; o1[2]=s[6]+bv[6]; o1[3]=s[7]+bv[7];
    *(f32x4*)(out + g) = o0;
    *(f32x4*)(out + g + 4) = o1;
}

extern "C" void kernel_launch(void* const* d_in, const int* in_sizes, int n_in,
                              void* d_out, int out_size, void* d_ws, size_t ws_size,
                              hipStream_t stream) {
    const float* Hv   = (const float*)d_in[0];
    const float* He   = (const float*)d_in[1];
    // d_in[2] = adj_e (unused by the reference)
    const float* adjv = (const float*)d_in[3];
    const float* T    = (const float*)d_in[4];
    const float* Wf   = (const float*)d_in[5];
    const float* p    = (const float*)d_in[6];
    const float* bias = (const float*)d_in[7];
    float* out = (float*)d_out;

    char* ws = (char*)d_ws;
    float* gate = (float*)(ws);                      //   32 KB
    short* Hvb  = (short*)(ws + 32768);              //    8 MB
    short* Wt   = (short*)(ws + 8421376);            //    8 MB  (HW^T, [512][8192])
    short* Tg   = (short*)(ws + 16809984);           //  128 MB
    short* Tb   = (short*)(ws + 151027712);          //  128 MB
    short* Cb   = (short*)(ws + 285245440);          //  128 MB
    short* WTb  = (short*)(ws + 285245440);          // aliased with Cb (consumed early)
    // diag partials (64 MB): alias Tg[0:64MB] — gemm256_ks only READS Tg rows >= 4096
    float* part = (float*)(ws + 16809984);
    // final-GEMM partials (64 MB): same region, used after Tg is fully dead
    float* part2 = (float*)(ws + 16809984);

    // second tuple output: H_e passthrough
    hipMemcpyAsync(out + (size_t)NV * DIM, He, (size_t)NE * DIM * sizeof(float),
                   hipMemcpyDeviceToDevice, stream);

    gate_kernel<<<NE / 4, 256, 0, stream>>>(He, p, gate);
    convert_T<<<(NV * (NE / 8)) / 256, 256, 0, stream>>>(T, gate, Tg, Tb);
    to_bf16<<<(NV * DIM / 8) / 256, 256, 0, stream>>>(Hv, Hvb);
    wT_bf16<<<dim3(8, 8), 256, 0, stream>>>(Wf, WTb);

    // Wt[j][k] = sum_c WT[j][c] * Hvb[k][c] = (Hv@W)^T   (M=512, N=8192, K=512)
    gemm_bt<2><<<(DIM / 128) * (NV / 128), 256, 0, stream>>>(
        WTb, Hvb, DIM, NV, DIM, Wt, nullptr, nullptr);

    // C = 0.5*adjusted_A + 0.5*adj_v fused into (Tg @ Tb^T), symmetric-triangular:
    // 496 upper tiles + 16 diag (bi<16) = 512 blocks (2 perfect machine rounds)
    gemm256<<<512, 512, 0, stream>>>(Tg, Tb, adjv, Cb);
    // remaining 16 diag tiles (bi>=16) as 16-way K-split (1 full round)
    gemm256_ks<<<256, 512, 0, stream>>>(Tg, Tb, part);
    reduce_diag<<<512, 256, 0, stream>>>(part, adjv, Cb);

    // out = C @ HW + bias: 256^2-tile 8-phase, 4-way K-split (1 round) + reduce
    gemm_fin<<<256, 512, 0, stream>>>(Cb, Wt, part2);
    reduce_out<<<(NV * DIM / 8) / 256, 256, 0, stream>>>(part2, bias, out);
}